// Round 3
// baseline (429.136 us; speedup 1.0000x reference)
//
#include <hip/hip_runtime.h>
#include <stdint.h>

#define N_EX 131072
#define DIM 128
#define NC 8192
#define NW 8192
#define LOG2E 1.4426950408889634f
#define LN2   0.6931471805599453f

typedef __attribute__((ext_vector_type(8))) __bf16 bf16x8;
typedef __attribute__((ext_vector_type(8))) unsigned short us8;
typedef __attribute__((ext_vector_type(4))) unsigned short us4;
typedef __attribute__((ext_vector_type(4))) float f32x4;

__device__ __forceinline__ unsigned short f2bf(float f) {
    union { float f; unsigned u; } v; v.f = f;
    unsigned u = v.u;
    unsigned r = u + 0x7fffu + ((u >> 16) & 1u);  // round-nearest-even
    return (unsigned short)(r >> 16);
}
__device__ __forceinline__ float bf2f(unsigned lo16) {
    union { unsigned u; float f; } x; x.u = lo16 << 16; return x.f;
}
__device__ __forceinline__ float fexp2(float x) { return __builtin_amdgcn_exp2f(x); }
__device__ __forceinline__ float flog2(float x) { return __builtin_amdgcn_logf(x); }

// ---------------------------------------------------------------- count + dedupe
__global__ void k_count(const int* __restrict__ cid, const int* __restrict__ wid,
                        int* cnt_c, int* cnt_w, unsigned* bitmask,
                        int* u_row, int* u_col, unsigned* pairs, int* n_unique) {
    int i = blockIdx.x * blockDim.x + threadIdx.x;
    if (i >= N_EX) return;
    int c = cid[i], w = wid[i];
    atomicAdd(&cnt_c[c], 1);
    atomicAdd(&cnt_w[w], 1);
    unsigned key = ((unsigned)c << 13) | (unsigned)w;   // c,w < 8192
    unsigned bit = 1u << (key & 31);
    unsigned old = atomicOr(&bitmask[key >> 5], bit);
    if (!(old & bit)) {   // first claimant owns this unique pair
        int p = atomicAdd(n_unique, 1);
        pairs[p] = key;
        atomicAdd(&u_row[c], 1);
        atomicAdd(&u_col[w], 1);
    }
}

// ---------------------------------------------------------------- exclusive scan (8192 ints), blockIdx.x selects side
__global__ void k_scan(const int* __restrict__ cnt_c, const int* __restrict__ cnt_w,
                       int* off_c, int* off_w, int* cur_c, int* cur_w) {
    const int* cnt = blockIdx.x ? cnt_w : cnt_c;
    int* offs = blockIdx.x ? off_w : off_c;
    int* cur  = blockIdx.x ? cur_w : cur_c;
    __shared__ int sh[1024];
    int t = threadIdx.x;          // 1024 threads, 8 elems each
    int loc[8]; int s = 0;
#pragma unroll
    for (int j = 0; j < 8; j++) { loc[j] = s; s += cnt[t * 8 + j]; }
    sh[t] = s; __syncthreads();
    for (int o = 1; o < 1024; o <<= 1) {
        int v = (t >= o) ? sh[t - o] : 0;
        __syncthreads();
        sh[t] += v;
        __syncthreads();
    }
    int pre = t ? sh[t - 1] : 0;
#pragma unroll
    for (int j = 0; j < 8; j++) { int v = pre + loc[j]; offs[t * 8 + j] = v; cur[t * 8 + j] = v; }
}

// ---------------------------------------------------------------- CSR scatter
__global__ void k_scatter(const int* __restrict__ cid, const int* __restrict__ wid,
                          int* cur_c, int* cur_w, int* rl_c, int* rl_w) {
    int i = blockIdx.x * blockDim.x + threadIdx.x;
    if (i < N_EX) {
        int c = cid[i]; int p = atomicAdd(&cur_c[c], 1); rl_c[p] = i;
    } else if (i < 2 * N_EX) {
        int j = i - N_EX; int w = wid[j]; int p = atomicAdd(&cur_w[w], 1); rl_w[p] = j;
    }
}

// ---------------------------------------------------------------- per-segment mean -> bf16 emb
// csv side pre-scaled by (1/T)*log2(e) so downstream logits are base-2.
// 32 lanes per segment (float4/lane), 8 segments per 256-thread block.
__global__ void k_gather(const float* __restrict__ f1, const float* __restrict__ f2,
                         const int* __restrict__ off_c, const int* __restrict__ off_w,
                         const int* __restrict__ cnt_c, const int* __restrict__ cnt_w,
                         const int* __restrict__ rl_c, const int* __restrict__ rl_w,
                         unsigned short* emb_c, unsigned short* emb_w) {
    int tid = threadIdx.x;
    int seg = blockIdx.x * 8 + (tid >> 5);
    int l32 = tid & 31;
    const float* f = blockIdx.y ? f2 : f1;
    const int* off = blockIdx.y ? off_w : off_c;
    const int* cnt = blockIdx.y ? cnt_w : cnt_c;
    const int* rl  = blockIdx.y ? rl_w  : rl_c;
    unsigned short* emb = blockIdx.y ? emb_w : emb_c;
    int n = cnt[seg], o = off[seg];
    float4 a = make_float4(0.f, 0.f, 0.f, 0.f);
    int j = 0;
    for (; j + 4 <= n; j += 4) {
        int i0 = rl[o + j], i1 = rl[o + j + 1], i2 = rl[o + j + 2], i3 = rl[o + j + 3];
        float4 v0 = *((const float4*)(f + (long)i0 * DIM) + l32);
        float4 v1 = *((const float4*)(f + (long)i1 * DIM) + l32);
        float4 v2 = *((const float4*)(f + (long)i2 * DIM) + l32);
        float4 v3 = *((const float4*)(f + (long)i3 * DIM) + l32);
        a.x += v0.x + v1.x + v2.x + v3.x;
        a.y += v0.y + v1.y + v2.y + v3.y;
        a.z += v0.z + v1.z + v2.z + v3.z;
        a.w += v0.w + v1.w + v2.w + v3.w;
    }
    for (; j < n; j++) {
        float4 v = *((const float4*)(f + (long)rl[o + j] * DIM) + l32);
        a.x += v.x; a.y += v.y; a.z += v.z; a.w += v.w;
    }
    int dn = n > 1 ? n : 1;
    float scale = (blockIdx.y ? 1.0f : 10.0f * LOG2E) / (float)dn;
    us4 hv = (us4){f2bf(a.x * scale), f2bf(a.y * scale), f2bf(a.z * scale), f2bf(a.w * scale)};
    *(us4*)(emb + (long)seg * DIM + l32 * 4) = hv;
}

// ---------------------------------------------------------------- bf16 MFMA GEMM + per-tile softmax partials
// 128x128 block tile staged to LDS (64 KB) via global_load_lds w=16.
// LDS layout: row-major 256 B rows, 16 B chunks rotated by row: phys_chunk = (log_chunk + row) & 15
// (store is lane-contiguous as global_load_lds requires; reads land 2-way bank-aliased = free).
// 4 waves, each 64x64 via 4x4 of 16x16x32 mfma. Logits are base-2 (log2e folded into emb_c).
// Epilogue: single stabilizer m = tile max, e = exp2(l - m), row/col partial (m, sum).
// rowpart: [8192][128] float2, slot = blockIdx.y*2 + colq ; colpart slot = blockIdx.x*2 + rowq
__global__ __launch_bounds__(256) void k_gemm(const unsigned short* __restrict__ ea,
                                              const unsigned short* __restrict__ eb,
                                              float2* __restrict__ rowpart,
                                              float2* __restrict__ colpart) {
    __shared__ unsigned short smem[2 * 128 * 128];   // A: shorts [0,16384), B: [16384,32768)
    int tid = threadIdx.x;
    int lane = tid & 63, wv = tid >> 6;
    int q = lane >> 4, l15 = lane & 15;
    int rowq = wv & 1, colq = wv >> 1;

    // ---- stage: each wave loads 32 rows of A and 32 of B (8+8 instrs, 4 rows per instr)
    {
        int sub = lane >> 4;       // row within 4-row group
        int cph = lane & 15;       // physical 16B chunk
#pragma unroll
        for (int j = 0; j < 8; j++) {
            int rbase = wv * 32 + j * 4;
            int r = rbase + sub;
            int cl = (cph - r) & 15;                   // logical chunk this lane fetches
            const unsigned short* ga = ea + ((long)(blockIdx.x * 128 + r)) * DIM + cl * 8;
            const unsigned short* gb = eb + ((long)(blockIdx.y * 128 + r)) * DIM + cl * 8;
            unsigned short* la = smem + rbase * 128;
            unsigned short* lb = smem + 16384 + rbase * 128;
            __builtin_amdgcn_global_load_lds((const __attribute__((address_space(1))) unsigned int*)ga,
                                             (__attribute__((address_space(3))) unsigned int*)la, 16, 0, 0);
            __builtin_amdgcn_global_load_lds((const __attribute__((address_space(1))) unsigned int*)gb,
                                             (__attribute__((address_space(3))) unsigned int*)lb, 16, 0, 0);
        }
    }
    __syncthreads();

    const unsigned short* Abase = smem + (rowq * 64 + l15) * 128;
    const unsigned short* Bbase = smem + 16384 + (colq * 64 + l15) * 128;

    f32x4 acc[4][4];
#pragma unroll
    for (int tm = 0; tm < 4; tm++)
#pragma unroll
        for (int tn = 0; tn < 4; tn++) acc[tm][tn] = (f32x4){0.f, 0.f, 0.f, 0.f};

#pragma unroll
    for (int s = 0; s < 4; s++) {
        int ph = (s * 4 + q + l15) & 15;   // shared by A-row and B-col (rows/cols ≡ l15 mod 16)
        bf16x8 a[4], b[4];
#pragma unroll
        for (int t = 0; t < 4; t++) {
            a[t] = __builtin_bit_cast(bf16x8, *(const us8*)(Abase + t * 2048 + ph * 8));
            b[t] = __builtin_bit_cast(bf16x8, *(const us8*)(Bbase + t * 2048 + ph * 8));
        }
#pragma unroll
        for (int tm = 0; tm < 4; tm++)
#pragma unroll
            for (int tn = 0; tn < 4; tn++)
                acc[tm][tn] = __builtin_amdgcn_mfma_f32_16x16x32_bf16(a[tm], b[tn], acc[tm][tn], 0, 0, 0);
    }

    // ---- epilogue: one stabilizer per wave tile
    float m;
    {
        f32x4 mv = acc[0][0];
#pragma unroll
        for (int tm = 0; tm < 4; tm++)
#pragma unroll
            for (int tn = 0; tn < 4; tn++) {
                if (tm == 0 && tn == 0) continue;
#pragma unroll
                for (int r = 0; r < 4; r++) mv[r] = fmaxf(mv[r], acc[tm][tn][r]);
            }
        m = fmaxf(fmaxf(mv[0], mv[1]), fmaxf(mv[2], mv[3]));
#pragma unroll
        for (int o = 1; o < 64; o <<= 1) m = fmaxf(m, __shfl_xor(m, o));
    }
    // e = exp2(l - m), in place
#pragma unroll
    for (int tm = 0; tm < 4; tm++)
#pragma unroll
        for (int tn = 0; tn < 4; tn++)
#pragma unroll
            for (int r = 0; r < 4; r++) acc[tm][tn][r] = fexp2(acc[tm][tn][r] - m);

    // rows: D layout col=lane&15, row=q*4+reg
#pragma unroll
    for (int tm = 0; tm < 4; tm++)
#pragma unroll
        for (int r = 0; r < 4; r++) {
            float s = acc[tm][0][r] + acc[tm][1][r] + acc[tm][2][r] + acc[tm][3][r];
            s += __shfl_xor(s, 1); s += __shfl_xor(s, 2);
            s += __shfl_xor(s, 4); s += __shfl_xor(s, 8);
            if (l15 == 0) {
                int row = blockIdx.x * 128 + rowq * 64 + tm * 16 + q * 4 + r;
                rowpart[(long)row * 128 + blockIdx.y * 2 + colq] = make_float2(m, s);
            }
        }
    // cols
#pragma unroll
    for (int tn = 0; tn < 4; tn++) {
        float s = 0.f;
#pragma unroll
        for (int tm = 0; tm < 4; tm++)
#pragma unroll
            for (int r = 0; r < 4; r++) s += acc[tm][tn][r];
        s += __shfl_xor(s, 16); s += __shfl_xor(s, 32);
        if (q == 0) {
            int col = blockIdx.y * 128 + colq * 64 + tn * 16 + l15;
            colpart[(long)col * 128 + blockIdx.x * 2 + rowq] = make_float2(m, s);
        }
    }
}

// ---------------------------------------------------------------- combine 128 (max,sum) partials -> base-2 LSE
// one wave per row/col; 16384 waves total (first 8192 = rows, next 8192 = cols)
__global__ void k_combine(const float4* __restrict__ rowpart, const float4* __restrict__ colpart,
                          float* __restrict__ lse_row, float* __restrict__ lse_col) {
    int gtid = blockIdx.x * blockDim.x + threadIdx.x;
    int gw = gtid >> 6, lane = gtid & 63;
    int side = gw >> 13;
    int idx = gw & 8191;
    const float4* part = side ? colpart : rowpart;   // [8192][64] float4 view of [8192][128] float2
    float4 v = part[(long)idx * 64 + lane];
    float m = fmaxf(v.x, v.z);
    float s = v.y * fexp2(v.x - m) + v.w * fexp2(v.z - m);
#pragma unroll
    for (int o = 1; o < 64; o <<= 1) {
        float om = __shfl_xor(m, o), os = __shfl_xor(s, o);
        float M = fmaxf(m, om);
        s = s * fexp2(m - M) + os * fexp2(om - M);
        m = M;
    }
    if (lane == 0) {
        float* dst = side ? lse_col : lse_row;
        dst[idx] = m + flog2(fmaxf(s, 1e-35f));
    }
}

// ---------------------------------------------------------------- per-unique-pair loss terms (one wave per pair)
// logits are base-2; term_nat = (l2 - lse2) * ln2 / U. Accumulates into facc[0] (axis0) and facc[1] (axis1).
__global__ void k_pairs(const unsigned* __restrict__ pairs, const int* __restrict__ n_unique,
                        const unsigned short* __restrict__ ea, const unsigned short* __restrict__ eb,
                        const float* __restrict__ lse_row, const float* __restrict__ lse_col,
                        const int* __restrict__ u_row, const int* __restrict__ u_col,
                        float* facc) {
    int gtid = blockIdx.x * blockDim.x + threadIdx.x;
    int wave = gtid >> 6, lane = gtid & 63;
    int nw = (gridDim.x * blockDim.x) >> 6;
    int M = *n_unique;
    float a0 = 0.f, a1 = 0.f;
    for (int p = wave; p < M; p += nw) {
        unsigned key = pairs[p];
        int c = key >> 13, w = key & 8191;
        unsigned av = *(const unsigned*)(ea + c * DIM + lane * 2);
        unsigned bv = *(const unsigned*)(eb + w * DIM + lane * 2);
        float s = bf2f(av & 0xffffu) * bf2f(bv & 0xffffu) + bf2f(av >> 16) * bf2f(bv >> 16);
        s += __shfl_xor(s, 1); s += __shfl_xor(s, 2); s += __shfl_xor(s, 4);
        s += __shfl_xor(s, 8); s += __shfl_xor(s, 16); s += __shfl_xor(s, 32);
        if (lane == 0) {
            a1 += (s - lse_row[c]) * LN2 / fmaxf((float)u_row[c], 1.f);
            a0 += (s - lse_col[w]) * LN2 / fmaxf((float)u_col[w], 1.f);
        }
    }
    if (lane == 0) {
        atomicAdd(&facc[0], a0);
        atomicAdd(&facc[1], a1);
    }
}

// ---------------------------------------------------------------- final scalar
__global__ void k_fin(const float* __restrict__ facc, float* __restrict__ out) {
    // loss = -0.5*(total0/NW + total1/NC)
    out[0] = -(facc[0] + facc[1]) * (0.5f / 8192.0f);
}

extern "C" void kernel_launch(void* const* d_in, const int* in_sizes, int n_in,
                              void* d_out, int out_size, void* d_ws, size_t ws_size,
                              hipStream_t stream) {
    const float* f1 = (const float*)d_in[0];
    const float* f2 = (const float*)d_in[1];
    const int* cid  = (const int*)d_in[2];
    const int* wid  = (const int*)d_in[3];
    float* out = (float*)d_out;

    char* ws = (char*)d_ws;
    size_t off = 0;
    auto alloc = [&](size_t bytes) -> void* {
        void* p = ws + off;
        off += (bytes + 255) & ~(size_t)255;
        return p;
    };
    // --- zero-initialized region (must be first; one memset) ---
    unsigned* bitmask = (unsigned*)alloc((size_t)NC * NW / 8);   // 8 MB
    int* cnt_c = (int*)alloc(NC * 4);
    int* cnt_w = (int*)alloc(NW * 4);
    int* u_row = (int*)alloc(NC * 4);
    int* u_col = (int*)alloc(NW * 4);
    float* facc = (float*)alloc(2 * 4);
    int* n_unique = (int*)alloc(4);
    size_t zero_bytes = off;
    // --- non-zeroed scratch (fully written before read) ---
    int* off_c = (int*)alloc(NC * 4);
    int* off_w = (int*)alloc(NW * 4);
    int* cur_c = (int*)alloc(NC * 4);
    int* cur_w = (int*)alloc(NW * 4);
    int* rl_c = (int*)alloc((size_t)N_EX * 4);
    int* rl_w = (int*)alloc((size_t)N_EX * 4);
    unsigned* pairs = (unsigned*)alloc((size_t)N_EX * 4);
    unsigned short* emb_c = (unsigned short*)alloc((size_t)NC * DIM * 2);
    unsigned short* emb_w = (unsigned short*)alloc((size_t)NW * DIM * 2);
    float2* rowpart = (float2*)alloc((size_t)NC * 128 * sizeof(float2));  // 8 MB
    float2* colpart = (float2*)alloc((size_t)NW * 128 * sizeof(float2));  // 8 MB
    float* lse_row = (float*)alloc(NC * 4);
    float* lse_col = (float*)alloc(NW * 4);

    hipMemsetAsync(d_ws, 0, zero_bytes, stream);

    k_count<<<(N_EX + 255) / 256, 256, 0, stream>>>(cid, wid, cnt_c, cnt_w, bitmask,
                                                    u_row, u_col, pairs, n_unique);
    k_scan<<<2, 1024, 0, stream>>>(cnt_c, cnt_w, off_c, off_w, cur_c, cur_w);
    k_scatter<<<(2 * N_EX + 255) / 256, 256, 0, stream>>>(cid, wid, cur_c, cur_w, rl_c, rl_w);
    k_gather<<<dim3(NC / 8, 2), 256, 0, stream>>>(f1, f2, off_c, off_w, cnt_c, cnt_w,
                                                  rl_c, rl_w, emb_c, emb_w);
    k_gemm<<<dim3(NC / 128, NW / 128), 256, 0, stream>>>(emb_c, emb_w, rowpart, colpart);
    k_combine<<<(16384 * 64) / 256, 256, 0, stream>>>((const float4*)rowpart, (const float4*)colpart,
                                                      lse_row, lse_col);
    k_pairs<<<1024, 256, 0, stream>>>(pairs, n_unique, emb_c, emb_w,
                                      lse_row, lse_col, u_row, u_col, facc);
    k_fin<<<1, 1, 0, stream>>>(facc, out);
}

// Round 4
// 307.142 us; speedup vs baseline: 1.3972x; 1.3972x over previous
//
#include <hip/hip_runtime.h>
#include <stdint.h>

#define N_EX 131072
#define DIM 128
#define NC 8192
#define NW 8192
#define LOG2E 1.4426950408889634f
#define LN2   0.6931471805599453f

typedef __attribute__((ext_vector_type(8))) __bf16 bf16x8;
typedef __attribute__((ext_vector_type(8))) unsigned short us8;
typedef __attribute__((ext_vector_type(4))) unsigned short us4;
typedef __attribute__((ext_vector_type(4))) float f32x4;

__device__ __forceinline__ unsigned short f2bf(float f) {
    union { float f; unsigned u; } v; v.f = f;
    unsigned u = v.u;
    unsigned r = u + 0x7fffu + ((u >> 16) & 1u);  // round-nearest-even
    return (unsigned short)(r >> 16);
}
__device__ __forceinline__ float bf2f(unsigned lo16) {
    union { unsigned u; float f; } x; x.u = lo16 << 16; return x.f;
}
__device__ __forceinline__ float fexp2(float x) { return __builtin_amdgcn_exp2f(x); }
__device__ __forceinline__ float flog2(float x) { return __builtin_amdgcn_logf(x); }

// ---------------------------------------------------------------- count + dedupe
__global__ void k_count(const int* __restrict__ cid, const int* __restrict__ wid,
                        int* cnt_c, int* cnt_w, unsigned* bitmask,
                        int* u_row, int* u_col, unsigned* pairs, int* n_unique) {
    int i = blockIdx.x * blockDim.x + threadIdx.x;
    if (i >= N_EX) return;
    int c = cid[i], w = wid[i];
    atomicAdd(&cnt_c[c], 1);
    atomicAdd(&cnt_w[w], 1);
    unsigned key = ((unsigned)c << 13) | (unsigned)w;   // c,w < 8192
    unsigned bit = 1u << (key & 31);
    unsigned old = atomicOr(&bitmask[key >> 5], bit);
    if (!(old & bit)) {   // first claimant owns this unique pair
        int p = atomicAdd(n_unique, 1);
        pairs[p] = key;
        atomicAdd(&u_row[c], 1);
        atomicAdd(&u_col[w], 1);
    }
}

// ---------------------------------------------------------------- exclusive scan (8192 ints), blockIdx.x selects side
__global__ void k_scan(const int* __restrict__ cnt_c, const int* __restrict__ cnt_w,
                       int* off_c, int* off_w, int* cur_c, int* cur_w) {
    const int* cnt = blockIdx.x ? cnt_w : cnt_c;
    int* offs = blockIdx.x ? off_w : off_c;
    int* cur  = blockIdx.x ? cur_w : cur_c;
    __shared__ int sh[1024];
    int t = threadIdx.x;          // 1024 threads, 8 elems each
    int loc[8]; int s = 0;
#pragma unroll
    for (int j = 0; j < 8; j++) { loc[j] = s; s += cnt[t * 8 + j]; }
    sh[t] = s; __syncthreads();
    for (int o = 1; o < 1024; o <<= 1) {
        int v = (t >= o) ? sh[t - o] : 0;
        __syncthreads();
        sh[t] += v;
        __syncthreads();
    }
    int pre = t ? sh[t - 1] : 0;
#pragma unroll
    for (int j = 0; j < 8; j++) { int v = pre + loc[j]; offs[t * 8 + j] = v; cur[t * 8 + j] = v; }
}

// ---------------------------------------------------------------- CSR scatter
__global__ void k_scatter(const int* __restrict__ cid, const int* __restrict__ wid,
                          int* cur_c, int* cur_w, int* rl_c, int* rl_w) {
    int i = blockIdx.x * blockDim.x + threadIdx.x;
    if (i < N_EX) {
        int c = cid[i]; int p = atomicAdd(&cur_c[c], 1); rl_c[p] = i;
    } else if (i < 2 * N_EX) {
        int j = i - N_EX; int w = wid[j]; int p = atomicAdd(&cur_w[w], 1); rl_w[p] = j;
    }
}

// ---------------------------------------------------------------- per-segment mean -> bf16 emb
// csv side pre-scaled by (1/T)*log2(e) so downstream logits are base-2.
// 32 lanes per segment (float4/lane), 8 segments per 256-thread block.
__global__ void k_gather(const float* __restrict__ f1, const float* __restrict__ f2,
                         const int* __restrict__ off_c, const int* __restrict__ off_w,
                         const int* __restrict__ cnt_c, const int* __restrict__ cnt_w,
                         const int* __restrict__ rl_c, const int* __restrict__ rl_w,
                         unsigned short* emb_c, unsigned short* emb_w) {
    int tid = threadIdx.x;
    int seg = blockIdx.x * 8 + (tid >> 5);
    int l32 = tid & 31;
    const float* f = blockIdx.y ? f2 : f1;
    const int* off = blockIdx.y ? off_w : off_c;
    const int* cnt = blockIdx.y ? cnt_w : cnt_c;
    const int* rl  = blockIdx.y ? rl_w  : rl_c;
    unsigned short* emb = blockIdx.y ? emb_w : emb_c;
    int n = cnt[seg], o = off[seg];
    float4 a = make_float4(0.f, 0.f, 0.f, 0.f);
    int j = 0;
    for (; j + 4 <= n; j += 4) {
        int i0 = rl[o + j], i1 = rl[o + j + 1], i2 = rl[o + j + 2], i3 = rl[o + j + 3];
        float4 v0 = *((const float4*)(f + (long)i0 * DIM) + l32);
        float4 v1 = *((const float4*)(f + (long)i1 * DIM) + l32);
        float4 v2 = *((const float4*)(f + (long)i2 * DIM) + l32);
        float4 v3 = *((const float4*)(f + (long)i3 * DIM) + l32);
        a.x += v0.x + v1.x + v2.x + v3.x;
        a.y += v0.y + v1.y + v2.y + v3.y;
        a.z += v0.z + v1.z + v2.z + v3.z;
        a.w += v0.w + v1.w + v2.w + v3.w;
    }
    for (; j < n; j++) {
        float4 v = *((const float4*)(f + (long)rl[o + j] * DIM) + l32);
        a.x += v.x; a.y += v.y; a.z += v.z; a.w += v.w;
    }
    int dn = n > 1 ? n : 1;
    float scale = (blockIdx.y ? 1.0f : 10.0f * LOG2E) / (float)dn;
    us4 hv = (us4){f2bf(a.x * scale), f2bf(a.y * scale), f2bf(a.z * scale), f2bf(a.w * scale)};
    *(us4*)(emb + (long)seg * DIM + l32 * 4) = hv;
}

// ---------------------------------------------------------------- bf16 MFMA GEMM + per-tile softmax partials
// 128x128 block tile staged to LDS (64 KB) via global_load_lds w=16.
// LDS layout: row-major 256 B rows, 16 B chunks rotated by row: phys_chunk = (log_chunk + row) & 15
// (store is lane-contiguous as global_load_lds requires; reads land 2-way bank-aliased = free).
// 4 waves, each 64x64 via 4x4 of 16x16x32 mfma. Logits are base-2 (log2e folded into emb_c).
// Epilogue: single stabilizer m = tile max, e = exp2(l - m), row/col partial (m, sum).
// rowpart: [8192][128] float2, slot = blockIdx.y*2 + colq ; colpart slot = blockIdx.x*2 + rowq
__global__ __launch_bounds__(256) void k_gemm(const unsigned short* __restrict__ ea,
                                              const unsigned short* __restrict__ eb,
                                              float2* __restrict__ rowpart,
                                              float2* __restrict__ colpart) {
    __shared__ unsigned short smem[2 * 128 * 128];   // A: shorts [0,16384), B: [16384,32768)
    int tid = threadIdx.x;
    int lane = tid & 63, wv = tid >> 6;
    int q = lane >> 4, l15 = lane & 15;
    int rowq = wv & 1, colq = wv >> 1;

    // ---- stage: each wave loads 32 rows of A and 32 of B (8+8 instrs, 4 rows per instr)
    {
        int sub = lane >> 4;       // row within 4-row group
        int cph = lane & 15;       // physical 16B chunk
#pragma unroll
        for (int j = 0; j < 8; j++) {
            int rbase = wv * 32 + j * 4;
            int r = rbase + sub;
            int cl = (cph - r) & 15;                   // logical chunk this lane fetches
            const unsigned short* ga = ea + ((long)(blockIdx.x * 128 + r)) * DIM + cl * 8;
            const unsigned short* gb = eb + ((long)(blockIdx.y * 128 + r)) * DIM + cl * 8;
            unsigned short* la = smem + rbase * 128;
            unsigned short* lb = smem + 16384 + rbase * 128;
            __builtin_amdgcn_global_load_lds((const __attribute__((address_space(1))) unsigned int*)ga,
                                             (__attribute__((address_space(3))) unsigned int*)la, 16, 0, 0);
            __builtin_amdgcn_global_load_lds((const __attribute__((address_space(1))) unsigned int*)gb,
                                             (__attribute__((address_space(3))) unsigned int*)lb, 16, 0, 0);
        }
    }
    __syncthreads();

    const unsigned short* Abase = smem + (rowq * 64 + l15) * 128;
    const unsigned short* Bbase = smem + 16384 + (colq * 64 + l15) * 128;

    f32x4 acc[4][4];
#pragma unroll
    for (int tm = 0; tm < 4; tm++)
#pragma unroll
        for (int tn = 0; tn < 4; tn++) acc[tm][tn] = (f32x4){0.f, 0.f, 0.f, 0.f};

#pragma unroll
    for (int s = 0; s < 4; s++) {
        int ph = (s * 4 + q + l15) & 15;   // shared by A-row and B-col (rows/cols ≡ l15 mod 16)
        bf16x8 a[4], b[4];
#pragma unroll
        for (int t = 0; t < 4; t++) {
            a[t] = __builtin_bit_cast(bf16x8, *(const us8*)(Abase + t * 2048 + ph * 8));
            b[t] = __builtin_bit_cast(bf16x8, *(const us8*)(Bbase + t * 2048 + ph * 8));
        }
#pragma unroll
        for (int tm = 0; tm < 4; tm++)
#pragma unroll
            for (int tn = 0; tn < 4; tn++)
                acc[tm][tn] = __builtin_amdgcn_mfma_f32_16x16x32_bf16(a[tm], b[tn], acc[tm][tn], 0, 0, 0);
    }

    // ---- epilogue: one stabilizer per wave tile
    float m;
    {
        f32x4 mv = acc[0][0];
#pragma unroll
        for (int tm = 0; tm < 4; tm++)
#pragma unroll
            for (int tn = 0; tn < 4; tn++) {
                if (tm == 0 && tn == 0) continue;
#pragma unroll
                for (int r = 0; r < 4; r++) mv[r] = fmaxf(mv[r], acc[tm][tn][r]);
            }
        m = fmaxf(fmaxf(mv[0], mv[1]), fmaxf(mv[2], mv[3]));
#pragma unroll
        for (int o = 1; o < 64; o <<= 1) m = fmaxf(m, __shfl_xor(m, o));
    }
    // e = exp2(l - m), in place
#pragma unroll
    for (int tm = 0; tm < 4; tm++)
#pragma unroll
        for (int tn = 0; tn < 4; tn++)
#pragma unroll
            for (int r = 0; r < 4; r++) acc[tm][tn][r] = fexp2(acc[tm][tn][r] - m);

    // rows: D layout col=lane&15, row=q*4+reg
#pragma unroll
    for (int tm = 0; tm < 4; tm++)
#pragma unroll
        for (int r = 0; r < 4; r++) {
            float s = acc[tm][0][r] + acc[tm][1][r] + acc[tm][2][r] + acc[tm][3][r];
            s += __shfl_xor(s, 1); s += __shfl_xor(s, 2);
            s += __shfl_xor(s, 4); s += __shfl_xor(s, 8);
            if (l15 == 0) {
                int row = blockIdx.x * 128 + rowq * 64 + tm * 16 + q * 4 + r;
                rowpart[(long)row * 128 + blockIdx.y * 2 + colq] = make_float2(m, s);
            }
        }
    // cols
#pragma unroll
    for (int tn = 0; tn < 4; tn++) {
        float s = 0.f;
#pragma unroll
        for (int tm = 0; tm < 4; tm++)
#pragma unroll
            for (int r = 0; r < 4; r++) s += acc[tm][tn][r];
        s += __shfl_xor(s, 16); s += __shfl_xor(s, 32);
        if (q == 0) {
            int col = blockIdx.y * 128 + colq * 64 + tn * 16 + l15;
            colpart[(long)col * 128 + blockIdx.x * 2 + rowq] = make_float2(m, s);
        }
    }
}

// ---------------------------------------------------------------- combine 128 (max,sum) partials -> base-2 LSE
// one wave per row/col; 16384 waves total (first 8192 = rows, next 8192 = cols)
__global__ void k_combine(const float4* __restrict__ rowpart, const float4* __restrict__ colpart,
                          float* __restrict__ lse_row, float* __restrict__ lse_col) {
    int gtid = blockIdx.x * blockDim.x + threadIdx.x;
    int gw = gtid >> 6, lane = gtid & 63;
    int side = gw >> 13;
    int idx = gw & 8191;
    const float4* part = side ? colpart : rowpart;   // [8192][64] float4 view of [8192][128] float2
    float4 v = part[(long)idx * 64 + lane];
    float m = fmaxf(v.x, v.z);
    float s = v.y * fexp2(v.x - m) + v.w * fexp2(v.z - m);
#pragma unroll
    for (int o = 1; o < 64; o <<= 1) {
        float om = __shfl_xor(m, o), os = __shfl_xor(s, o);
        float M = fmaxf(m, om);
        s = s * fexp2(m - M) + os * fexp2(om - M);
        m = M;
    }
    if (lane == 0) {
        float* dst = side ? lse_col : lse_row;
        dst[idx] = m + flog2(fmaxf(s, 1e-35f));
    }
}

// ---------------------------------------------------------------- per-unique-pair loss terms
// One pair per 16-lane quarter: us8 load = full 256 B embedding row per side.
// 4096 blocks x 4 waves x 4 quarters = 65536 pairs/sweep -> 2 iterations at M~130K.
// No atomics: per-wave -> per-block LDS reduce -> block_part[blockIdx.x].
__global__ __launch_bounds__(256) void k_pairs(const unsigned* __restrict__ pairs,
                                               const int* __restrict__ n_unique,
                                               const unsigned short* __restrict__ ea,
                                               const unsigned short* __restrict__ eb,
                                               const float* __restrict__ lse_row,
                                               const float* __restrict__ lse_col,
                                               const int* __restrict__ u_row,
                                               const int* __restrict__ u_col,
                                               float2* __restrict__ block_part) {
    int tid = threadIdx.x;
    int lane = tid & 63;
    int quarter = lane >> 4, l16 = lane & 15;
    int gwave = (blockIdx.x * 256 + tid) >> 6;     // 0..16383
    int M = *n_unique;
    float a0 = 0.f, a1 = 0.f;
    for (int base = gwave * 4; base < M; base += 65536) {
        int p = base + quarter;
        bool valid = p < M;
        unsigned key = valid ? pairs[p] : 0u;
        int c = key >> 13, w = key & 8191;
        us8 av = *(const us8*)(ea + (long)c * DIM + l16 * 8);
        us8 bv = *(const us8*)(eb + (long)w * DIM + l16 * 8);
        float s = 0.f;
#pragma unroll
        for (int j = 0; j < 8; j++) s += bf2f((unsigned)av[j]) * bf2f((unsigned)bv[j]);
        s += __shfl_xor(s, 1); s += __shfl_xor(s, 2);
        s += __shfl_xor(s, 4); s += __shfl_xor(s, 8);
        if (valid & (l16 == 0)) {
            a1 += (s - lse_row[c]) * LN2 / fmaxf((float)u_row[c], 1.f);
            a0 += (s - lse_col[w]) * LN2 / fmaxf((float)u_col[w], 1.f);
        }
    }
    // sum the 4 quarter-leaders across the wave
    a0 += __shfl_xor(a0, 16); a0 += __shfl_xor(a0, 32);
    a1 += __shfl_xor(a1, 16); a1 += __shfl_xor(a1, 32);
    __shared__ float2 shp[4];
    if (lane == 0) shp[tid >> 6] = make_float2(a0, a1);
    __syncthreads();
    if (tid == 0) {
        float2 t = shp[0];
        t.x += shp[1].x + shp[2].x + shp[3].x;
        t.y += shp[1].y + shp[2].y + shp[3].y;
        block_part[blockIdx.x] = t;
    }
}

// ---------------------------------------------------------------- final scalar: reduce 4096 block partials
__global__ void k_fin(const float2* __restrict__ block_part, float* __restrict__ out) {
    __shared__ float2 sh[256];
    int t = threadIdx.x;
    float x = 0.f, y = 0.f;
    for (int i = t; i < 4096; i += 256) { float2 v = block_part[i]; x += v.x; y += v.y; }
    sh[t] = make_float2(x, y); __syncthreads();
    for (int o = 128; o > 0; o >>= 1) {
        if (t < o) { sh[t].x += sh[t + o].x; sh[t].y += sh[t + o].y; }
        __syncthreads();
    }
    if (t == 0) {
        // loss = -0.5*(total0/NW + total1/NC)
        out[0] = -(sh[0].x + sh[0].y) * (0.5f / 8192.0f);
    }
}

extern "C" void kernel_launch(void* const* d_in, const int* in_sizes, int n_in,
                              void* d_out, int out_size, void* d_ws, size_t ws_size,
                              hipStream_t stream) {
    const float* f1 = (const float*)d_in[0];
    const float* f2 = (const float*)d_in[1];
    const int* cid  = (const int*)d_in[2];
    const int* wid  = (const int*)d_in[3];
    float* out = (float*)d_out;

    char* ws = (char*)d_ws;
    size_t off = 0;
    auto alloc = [&](size_t bytes) -> void* {
        void* p = ws + off;
        off += (bytes + 255) & ~(size_t)255;
        return p;
    };
    // --- zero-initialized region (must be first; one memset) ---
    unsigned* bitmask = (unsigned*)alloc((size_t)NC * NW / 8);   // 8 MB
    int* cnt_c = (int*)alloc(NC * 4);
    int* cnt_w = (int*)alloc(NW * 4);
    int* u_row = (int*)alloc(NC * 4);
    int* u_col = (int*)alloc(NW * 4);
    int* n_unique = (int*)alloc(4);
    size_t zero_bytes = off;
    // --- non-zeroed scratch (fully written before read) ---
    int* off_c = (int*)alloc(NC * 4);
    int* off_w = (int*)alloc(NW * 4);
    int* cur_c = (int*)alloc(NC * 4);
    int* cur_w = (int*)alloc(NW * 4);
    int* rl_c = (int*)alloc((size_t)N_EX * 4);
    int* rl_w = (int*)alloc((size_t)N_EX * 4);
    unsigned* pairs = (unsigned*)alloc((size_t)N_EX * 4);
    unsigned short* emb_c = (unsigned short*)alloc((size_t)NC * DIM * 2);
    unsigned short* emb_w = (unsigned short*)alloc((size_t)NW * DIM * 2);
    float2* rowpart = (float2*)alloc((size_t)NC * 128 * sizeof(float2));  // 8 MB
    float2* colpart = (float2*)alloc((size_t)NW * 128 * sizeof(float2));  // 8 MB
    float* lse_row = (float*)alloc(NC * 4);
    float* lse_col = (float*)alloc(NW * 4);
    float2* block_part = (float2*)alloc(4096 * sizeof(float2));

    hipMemsetAsync(d_ws, 0, zero_bytes, stream);

    k_count<<<(N_EX + 255) / 256, 256, 0, stream>>>(cid, wid, cnt_c, cnt_w, bitmask,
                                                    u_row, u_col, pairs, n_unique);
    k_scan<<<2, 1024, 0, stream>>>(cnt_c, cnt_w, off_c, off_w, cur_c, cur_w);
    k_scatter<<<(2 * N_EX + 255) / 256, 256, 0, stream>>>(cid, wid, cur_c, cur_w, rl_c, rl_w);
    k_gather<<<dim3(NC / 8, 2), 256, 0, stream>>>(f1, f2, off_c, off_w, cnt_c, cnt_w,
                                                  rl_c, rl_w, emb_c, emb_w);
    k_gemm<<<dim3(NC / 128, NW / 128), 256, 0, stream>>>(emb_c, emb_w, rowpart, colpart);
    k_combine<<<(16384 * 64) / 256, 256, 0, stream>>>((const float4*)rowpart, (const float4*)colpart,
                                                      lse_row, lse_col);
    k_pairs<<<4096, 256, 0, stream>>>(pairs, n_unique, emb_c, emb_w,
                                      lse_row, lse_col, u_row, u_col, block_part);
    k_fin<<<1, 256, 0, stream>>>(block_part, out);
}

// Round 5
// 272.468 us; speedup vs baseline: 1.5750x; 1.1273x over previous
//
#include <hip/hip_runtime.h>
#include <stdint.h>

#define N_EX 131072
#define DIM 128
#define NC 8192
#define NW 8192
#define LOG2E 1.4426950408889634f
#define LN2   0.6931471805599453f

typedef __attribute__((ext_vector_type(8))) __bf16 bf16x8;
typedef __attribute__((ext_vector_type(8))) unsigned short us8;
typedef __attribute__((ext_vector_type(4))) unsigned short us4;
typedef __attribute__((ext_vector_type(4))) float f32x4;

__device__ __forceinline__ unsigned short f2bf(float f) {
    union { float f; unsigned u; } v; v.f = f;
    unsigned u = v.u;
    unsigned r = u + 0x7fffu + ((u >> 16) & 1u);  // round-nearest-even
    return (unsigned short)(r >> 16);
}
__device__ __forceinline__ float bf2f(unsigned lo16) {
    union { unsigned u; float f; } x; x.u = lo16 << 16; return x.f;
}
__device__ __forceinline__ float fexp2(float x) { return __builtin_amdgcn_exp2f(x); }
__device__ __forceinline__ float flog2(float x) { return __builtin_amdgcn_logf(x); }

// DPP row_ror butterfly steps (16-lane rows, VALU pipe — no DS latency).
// ror:8,4,2,1 sequence gives every lane the full 16-lane reduction.
template<int CTRL>
__device__ __forceinline__ float dpp_addf(float x) {
    int t = __builtin_amdgcn_update_dpp(0, __builtin_bit_cast(int, x), CTRL, 0xf, 0xf, true);
    return x + __builtin_bit_cast(float, t);
}
template<int CTRL>
__device__ __forceinline__ float dpp_maxf(float x) {
    int t = __builtin_amdgcn_update_dpp(0, __builtin_bit_cast(int, x), CTRL, 0xf, 0xf, true);
    return fmaxf(x, __builtin_bit_cast(float, t));
}
__device__ __forceinline__ float row16_sum(float s) {
    s = dpp_addf<0x128>(s); s = dpp_addf<0x124>(s);
    s = dpp_addf<0x122>(s); s = dpp_addf<0x121>(s);
    return s;   // all 16 lanes of each row hold the row sum
}
__device__ __forceinline__ float row16_max(float m) {
    m = dpp_maxf<0x128>(m); m = dpp_maxf<0x124>(m);
    m = dpp_maxf<0x122>(m); m = dpp_maxf<0x121>(m);
    return m;
}

// ---------------------------------------------------------------- count + dedupe (flag, no compaction)
__global__ void k_count(const int* __restrict__ cid, const int* __restrict__ wid,
                        int* cnt_c, int* cnt_w, unsigned* bitmask,
                        int* u_row, int* u_col, int* __restrict__ isuniq) {
    int i = blockIdx.x * blockDim.x + threadIdx.x;
    if (i >= N_EX) return;
    int c = cid[i], w = wid[i];
    atomicAdd(&cnt_c[c], 1);
    atomicAdd(&cnt_w[w], 1);
    unsigned key = ((unsigned)c << 13) | (unsigned)w;   // c,w < 8192
    unsigned bit = 1u << (key & 31);
    unsigned old = atomicOr(&bitmask[key >> 5], bit);
    int win = (old & bit) ? 0 : 1;   // first claimant owns this unique pair
    isuniq[i] = win;
    if (win) {
        atomicAdd(&u_row[c], 1);
        atomicAdd(&u_col[w], 1);
    }
}

// ---------------------------------------------------------------- exclusive scan (8192 ints), blockIdx.x selects side
__global__ void k_scan(const int* __restrict__ cnt_c, const int* __restrict__ cnt_w,
                       int* off_c, int* off_w, int* cur_c, int* cur_w) {
    const int* cnt = blockIdx.x ? cnt_w : cnt_c;
    int* offs = blockIdx.x ? off_w : off_c;
    int* cur  = blockIdx.x ? cur_w : cur_c;
    __shared__ int sh[1024];
    int t = threadIdx.x;          // 1024 threads, 8 elems each
    int loc[8]; int s = 0;
#pragma unroll
    for (int j = 0; j < 8; j++) { loc[j] = s; s += cnt[t * 8 + j]; }
    sh[t] = s; __syncthreads();
    for (int o = 1; o < 1024; o <<= 1) {
        int v = (t >= o) ? sh[t - o] : 0;
        __syncthreads();
        sh[t] += v;
        __syncthreads();
    }
    int pre = t ? sh[t - 1] : 0;
#pragma unroll
    for (int j = 0; j < 8; j++) { int v = pre + loc[j]; offs[t * 8 + j] = v; cur[t * 8 + j] = v; }
}

// ---------------------------------------------------------------- CSR scatter
__global__ void k_scatter(const int* __restrict__ cid, const int* __restrict__ wid,
                          int* cur_c, int* cur_w, int* rl_c, int* rl_w) {
    int i = blockIdx.x * blockDim.x + threadIdx.x;
    if (i < N_EX) {
        int c = cid[i]; int p = atomicAdd(&cur_c[c], 1); rl_c[p] = i;
    } else if (i < 2 * N_EX) {
        int j = i - N_EX; int w = wid[j]; int p = atomicAdd(&cur_w[w], 1); rl_w[p] = j;
    }
}

// ---------------------------------------------------------------- per-segment mean -> bf16 emb
// csv side pre-scaled by (1/T)*log2(e) so downstream logits are base-2.
// 32 lanes per segment (float4/lane), 8 segments per 256-thread block.
__global__ void k_gather(const float* __restrict__ f1, const float* __restrict__ f2,
                         const int* __restrict__ off_c, const int* __restrict__ off_w,
                         const int* __restrict__ cnt_c, const int* __restrict__ cnt_w,
                         const int* __restrict__ rl_c, const int* __restrict__ rl_w,
                         unsigned short* emb_c, unsigned short* emb_w) {
    int tid = threadIdx.x;
    int seg = blockIdx.x * 8 + (tid >> 5);
    int l32 = tid & 31;
    const float* f = blockIdx.y ? f2 : f1;
    const int* off = blockIdx.y ? off_w : off_c;
    const int* cnt = blockIdx.y ? cnt_w : cnt_c;
    const int* rl  = blockIdx.y ? rl_w  : rl_c;
    unsigned short* emb = blockIdx.y ? emb_w : emb_c;
    int n = cnt[seg], o = off[seg];
    float4 a = make_float4(0.f, 0.f, 0.f, 0.f);
    int j = 0;
    for (; j + 4 <= n; j += 4) {
        int i0 = rl[o + j], i1 = rl[o + j + 1], i2 = rl[o + j + 2], i3 = rl[o + j + 3];
        float4 v0 = *((const float4*)(f + (long)i0 * DIM) + l32);
        float4 v1 = *((const float4*)(f + (long)i1 * DIM) + l32);
        float4 v2 = *((const float4*)(f + (long)i2 * DIM) + l32);
        float4 v3 = *((const float4*)(f + (long)i3 * DIM) + l32);
        a.x += v0.x + v1.x + v2.x + v3.x;
        a.y += v0.y + v1.y + v2.y + v3.y;
        a.z += v0.z + v1.z + v2.z + v3.z;
        a.w += v0.w + v1.w + v2.w + v3.w;
    }
    for (; j < n; j++) {
        float4 v = *((const float4*)(f + (long)rl[o + j] * DIM) + l32);
        a.x += v.x; a.y += v.y; a.z += v.z; a.w += v.w;
    }
    int dn = n > 1 ? n : 1;
    float scale = (blockIdx.y ? 1.0f : 10.0f * LOG2E) / (float)dn;
    us4 hv = (us4){f2bf(a.x * scale), f2bf(a.y * scale), f2bf(a.z * scale), f2bf(a.w * scale)};
    *(us4*)(emb + (long)seg * DIM + l32 * 4) = hv;
}

// ---------------------------------------------------------------- bf16 MFMA GEMM + per-tile softmax partials
// 128x128 block tile staged to LDS (64 KB) via global_load_lds w=16, row-rotated 16B chunks.
// 4 waves, each 64x64 via 4x4 of 16x16x32 mfma. Logits are base-2 (log2e folded into emb_c).
// Epilogue: per-wave max (DPP+2 swizzle), exp2(l-m), DPP row sums / in-lane col sums.
// rowpart: [8192][128] float2, slot = blockIdx.y*2 + colq ; colpart slot = blockIdx.x*2 + rowq
__global__ __launch_bounds__(256) void k_gemm(const unsigned short* __restrict__ ea,
                                              const unsigned short* __restrict__ eb,
                                              float2* __restrict__ rowpart,
                                              float2* __restrict__ colpart) {
    __shared__ unsigned short smem[2 * 128 * 128];   // A: shorts [0,16384), B: [16384,32768)
    int tid = threadIdx.x;
    int lane = tid & 63, wv = tid >> 6;
    int q = lane >> 4, l15 = lane & 15;
    int rowq = wv & 1, colq = wv >> 1;

    // ---- stage: each wave loads 32 rows of A and 32 of B (8+8 instrs, 4 rows per instr)
    {
        int sub = lane >> 4;       // row within 4-row group
        int cph = lane & 15;       // physical 16B chunk
#pragma unroll
        for (int j = 0; j < 8; j++) {
            int rbase = wv * 32 + j * 4;
            int r = rbase + sub;
            int cl = (cph - r) & 15;                   // logical chunk this lane fetches
            const unsigned short* ga = ea + ((long)(blockIdx.x * 128 + r)) * DIM + cl * 8;
            const unsigned short* gb = eb + ((long)(blockIdx.y * 128 + r)) * DIM + cl * 8;
            unsigned short* la = smem + rbase * 128;
            unsigned short* lb = smem + 16384 + rbase * 128;
            __builtin_amdgcn_global_load_lds((const __attribute__((address_space(1))) unsigned int*)ga,
                                             (__attribute__((address_space(3))) unsigned int*)la, 16, 0, 0);
            __builtin_amdgcn_global_load_lds((const __attribute__((address_space(1))) unsigned int*)gb,
                                             (__attribute__((address_space(3))) unsigned int*)lb, 16, 0, 0);
        }
    }
    __syncthreads();

    const unsigned short* Abase = smem + (rowq * 64 + l15) * 128;
    const unsigned short* Bbase = smem + 16384 + (colq * 64 + l15) * 128;

    f32x4 acc[4][4];
#pragma unroll
    for (int tm = 0; tm < 4; tm++)
#pragma unroll
        for (int tn = 0; tn < 4; tn++) acc[tm][tn] = (f32x4){0.f, 0.f, 0.f, 0.f};

#pragma unroll
    for (int s = 0; s < 4; s++) {
        int ph = (s * 4 + q + l15) & 15;   // shared by A-row and B-col (rows/cols ≡ l15 mod 16)
        bf16x8 a[4], b[4];
#pragma unroll
        for (int t = 0; t < 4; t++) {
            a[t] = __builtin_bit_cast(bf16x8, *(const us8*)(Abase + t * 2048 + ph * 8));
            b[t] = __builtin_bit_cast(bf16x8, *(const us8*)(Bbase + t * 2048 + ph * 8));
        }
#pragma unroll
        for (int tm = 0; tm < 4; tm++)
#pragma unroll
            for (int tn = 0; tn < 4; tn++)
                acc[tm][tn] = __builtin_amdgcn_mfma_f32_16x16x32_bf16(a[tm], b[tn], acc[tm][tn], 0, 0, 0);
    }

    // ---- epilogue: one stabilizer per wave tile (DPP in-row + 2 swizzles cross-row)
    float m;
    {
        f32x4 mv = acc[0][0];
#pragma unroll
        for (int tm = 0; tm < 4; tm++)
#pragma unroll
            for (int tn = 0; tn < 4; tn++) {
                if (tm == 0 && tn == 0) continue;
#pragma unroll
                for (int r = 0; r < 4; r++) mv[r] = fmaxf(mv[r], acc[tm][tn][r]);
            }
        m = fmaxf(fmaxf(mv[0], mv[1]), fmaxf(mv[2], mv[3]));
        m = row16_max(m);
        m = fmaxf(m, __shfl_xor(m, 16));
        m = fmaxf(m, __shfl_xor(m, 32));
    }
    // e = exp2(l - m), in place
#pragma unroll
    for (int tm = 0; tm < 4; tm++)
#pragma unroll
        for (int tn = 0; tn < 4; tn++)
#pragma unroll
            for (int r = 0; r < 4; r++) acc[tm][tn][r] = fexp2(acc[tm][tn][r] - m);

    // rows: D layout col=lane&15, row=q*4+reg; DPP row sums (VALU pipe, no DS chains)
#pragma unroll
    for (int tm = 0; tm < 4; tm++)
#pragma unroll
        for (int r = 0; r < 4; r++) {
            float s = acc[tm][0][r] + acc[tm][1][r] + acc[tm][2][r] + acc[tm][3][r];
            s = row16_sum(s);
            if (l15 == 0) {
                int row = blockIdx.x * 128 + rowq * 64 + tm * 16 + q * 4 + r;
                rowpart[(long)row * 128 + blockIdx.y * 2 + colq] = make_float2(m, s);
            }
        }
    // cols: in-lane sums then cross-row swizzles
#pragma unroll
    for (int tn = 0; tn < 4; tn++) {
        float s = 0.f;
#pragma unroll
        for (int tm = 0; tm < 4; tm++)
#pragma unroll
            for (int r = 0; r < 4; r++) s += acc[tm][tn][r];
        s += __shfl_xor(s, 16); s += __shfl_xor(s, 32);
        if (q == 0) {
            int col = blockIdx.y * 128 + colq * 64 + tn * 16 + l15;
            colpart[(long)col * 128 + blockIdx.x * 2 + rowq] = make_float2(m, s);
        }
    }
}

// ---------------------------------------------------------------- combine 128 (max,sum) partials -> base-2 LSE
// one wave per row/col; 16384 waves total (first 8192 = rows, next 8192 = cols)
__global__ void k_combine(const float4* __restrict__ rowpart, const float4* __restrict__ colpart,
                          float* __restrict__ lse_row, float* __restrict__ lse_col) {
    int gtid = blockIdx.x * blockDim.x + threadIdx.x;
    int gw = gtid >> 6, lane = gtid & 63;
    int side = gw >> 13;
    int idx = gw & 8191;
    const float4* part = side ? colpart : rowpart;   // [8192][64] float4 view of [8192][128] float2
    float4 v = part[(long)idx * 64 + lane];
    float m = fmaxf(v.x, v.z);
    float s = v.y * fexp2(v.x - m) + v.w * fexp2(v.z - m);
#pragma unroll
    for (int o = 1; o < 64; o <<= 1) {
        float om = __shfl_xor(m, o), os = __shfl_xor(s, o);
        float M = fmaxf(m, om);
        s = s * fexp2(m - M) + os * fexp2(om - M);
        m = M;
    }
    if (lane == 0) {
        float* dst = side ? lse_col : lse_row;
        dst[idx] = m + flog2(fmaxf(s, 1e-35f));
    }
}

// ---------------------------------------------------------------- per-example loss terms (flag-deduped)
// One example per 16-lane quarter: us8 load = full 256 B embedding row per side.
// 4096 blocks x 4 waves x 4 quarters = 65536 pairs/sweep -> exactly 2 iterations.
// No atomics: per-wave -> per-block LDS reduce -> block_part[blockIdx.x].
__global__ __launch_bounds__(256) void k_pairs(const int* __restrict__ cid,
                                               const int* __restrict__ wid,
                                               const int* __restrict__ isuniq,
                                               const unsigned short* __restrict__ ea,
                                               const unsigned short* __restrict__ eb,
                                               const float* __restrict__ lse_row,
                                               const float* __restrict__ lse_col,
                                               const int* __restrict__ u_row,
                                               const int* __restrict__ u_col,
                                               float2* __restrict__ block_part) {
    int tid = threadIdx.x;
    int lane = tid & 63;
    int quarter = lane >> 4, l16 = lane & 15;
    int gwave = (blockIdx.x * 256 + tid) >> 6;     // 0..16383
    float a0 = 0.f, a1 = 0.f;
#pragma unroll
    for (int base = gwave * 4; base < N_EX; base += 65536) {
        int p = base + quarter;
        int c = cid[p], w = wid[p];
        float flag = (float)isuniq[p];
        us8 av = *(const us8*)(ea + (long)c * DIM + l16 * 8);
        us8 bv = *(const us8*)(eb + (long)w * DIM + l16 * 8);
        float s = 0.f;
#pragma unroll
        for (int j = 0; j < 8; j++) s += bf2f((unsigned)av[j]) * bf2f((unsigned)bv[j]);
        s = row16_sum(s);
        if (l16 == 0) {
            a1 += flag * (s - lse_row[c]) * LN2 / fmaxf((float)u_row[c], 1.f);
            a0 += flag * (s - lse_col[w]) * LN2 / fmaxf((float)u_col[w], 1.f);
        }
    }
    // sum the 4 quarter-leaders across the wave
    a0 += __shfl_xor(a0, 16); a0 += __shfl_xor(a0, 32);
    a1 += __shfl_xor(a1, 16); a1 += __shfl_xor(a1, 32);
    __shared__ float2 shp[4];
    if (lane == 0) shp[tid >> 6] = make_float2(a0, a1);
    __syncthreads();
    if (tid == 0) {
        float2 t = shp[0];
        t.x += shp[1].x + shp[2].x + shp[3].x;
        t.y += shp[1].y + shp[2].y + shp[3].y;
        block_part[blockIdx.x] = t;
    }
}

// ---------------------------------------------------------------- final scalar: reduce 4096 block partials
__global__ void k_fin(const float2* __restrict__ block_part, float* __restrict__ out) {
    __shared__ float2 sh[256];
    int t = threadIdx.x;
    float x = 0.f, y = 0.f;
    for (int i = t; i < 4096; i += 256) { float2 v = block_part[i]; x += v.x; y += v.y; }
    sh[t] = make_float2(x, y); __syncthreads();
    for (int o = 128; o > 0; o >>= 1) {
        if (t < o) { sh[t].x += sh[t + o].x; sh[t].y += sh[t + o].y; }
        __syncthreads();
    }
    if (t == 0) {
        // loss = -0.5*(total0/NW + total1/NC)
        out[0] = -(sh[0].x + sh[0].y) * (0.5f / 8192.0f);
    }
}

extern "C" void kernel_launch(void* const* d_in, const int* in_sizes, int n_in,
                              void* d_out, int out_size, void* d_ws, size_t ws_size,
                              hipStream_t stream) {
    const float* f1 = (const float*)d_in[0];
    const float* f2 = (const float*)d_in[1];
    const int* cid  = (const int*)d_in[2];
    const int* wid  = (const int*)d_in[3];
    float* out = (float*)d_out;

    char* ws = (char*)d_ws;
    size_t off = 0;
    auto alloc = [&](size_t bytes) -> void* {
        void* p = ws + off;
        off += (bytes + 255) & ~(size_t)255;
        return p;
    };
    // --- zero-initialized region (must be first; one memset) ---
    unsigned* bitmask = (unsigned*)alloc((size_t)NC * NW / 8);   // 8 MB
    int* cnt_c = (int*)alloc(NC * 4);
    int* cnt_w = (int*)alloc(NW * 4);
    int* u_row = (int*)alloc(NC * 4);
    int* u_col = (int*)alloc(NW * 4);
    size_t zero_bytes = off;
    // --- non-zeroed scratch (fully written before read) ---
    int* off_c = (int*)alloc(NC * 4);
    int* off_w = (int*)alloc(NW * 4);
    int* cur_c = (int*)alloc(NC * 4);
    int* cur_w = (int*)alloc(NW * 4);
    int* rl_c = (int*)alloc((size_t)N_EX * 4);
    int* rl_w = (int*)alloc((size_t)N_EX * 4);
    int* isuniq = (int*)alloc((size_t)N_EX * 4);
    unsigned short* emb_c = (unsigned short*)alloc((size_t)NC * DIM * 2);
    unsigned short* emb_w = (unsigned short*)alloc((size_t)NW * DIM * 2);
    float2* rowpart = (float2*)alloc((size_t)NC * 128 * sizeof(float2));  // 8 MB
    float2* colpart = (float2*)alloc((size_t)NW * 128 * sizeof(float2));  // 8 MB
    float* lse_row = (float*)alloc(NC * 4);
    float* lse_col = (float*)alloc(NW * 4);
    float2* block_part = (float2*)alloc(4096 * sizeof(float2));

    hipMemsetAsync(d_ws, 0, zero_bytes, stream);

    k_count<<<(N_EX + 255) / 256, 256, 0, stream>>>(cid, wid, cnt_c, cnt_w, bitmask,
                                                    u_row, u_col, isuniq);
    k_scan<<<2, 1024, 0, stream>>>(cnt_c, cnt_w, off_c, off_w, cur_c, cur_w);
    k_scatter<<<(2 * N_EX + 255) / 256, 256, 0, stream>>>(cid, wid, cur_c, cur_w, rl_c, rl_w);
    k_gather<<<dim3(NC / 8, 2), 256, 0, stream>>>(f1, f2, off_c, off_w, cnt_c, cnt_w,
                                                  rl_c, rl_w, emb_c, emb_w);
    k_gemm<<<dim3(NC / 128, NW / 128), 256, 0, stream>>>(emb_c, emb_w, rowpart, colpart);
    k_combine<<<(16384 * 64) / 256, 256, 0, stream>>>((const float4*)rowpart, (const float4*)colpart,
                                                      lse_row, lse_col);
    k_pairs<<<4096, 256, 0, stream>>>(cid, wid, isuniq, emb_c, emb_w,
                                      lse_row, lse_col, u_row, u_col, block_part);
    k_fin<<<1, 256, 0, stream>>>(block_part, out);
}